// Round 5
// baseline (306.484 us; speedup 1.0000x reference)
//
#include <hip/hip_runtime.h>
#include <hip/hip_bf16.h>
#include <cstdint>

#define MDIM 32768
#define NDIM 1024
#define KDIM 1024
#define KC   512   // compacted K (2:4 structured mask -> 2 of every 4 cols active)

typedef float          f32x4 __attribute__((ext_vector_type(4)));
typedef short          s16x8 __attribute__((ext_vector_type(8)));
typedef unsigned short u16x4 __attribute__((ext_vector_type(4)));
typedef unsigned short u16x8 __attribute__((ext_vector_type(8)));

typedef __attribute__((address_space(1))) unsigned int gu32;
typedef __attribute__((address_space(3))) unsigned int lu32;

// fp32 -> bf16 round-to-nearest-even (inputs are finite; no NaN handling needed)
__device__ __forceinline__ unsigned short f2bf(float f) {
  unsigned int u = __builtin_bit_cast(unsigned int, f);
  u += 0x7fffu + ((u >> 16) & 1u);
  return (unsigned short)(u >> 16);
}

// Branchless 2-of-4 column selection from mask values (exactly 2 of m0..m3 are
// nonzero). Covers all six patterns.
__device__ __forceinline__ float sel_first(f32x4 v, f32x4 m) {
  return m[0] != 0.0f ? v[0] : (m[1] != 0.0f ? v[1] : v[2]);
}
__device__ __forceinline__ float sel_second(f32x4 v, f32x4 m) {
  return m[3] != 0.0f ? v[3] : (m[2] != 0.0f ? v[2] : v[1]);
}

// async global->LDS, 16 bytes per lane (global_load_lds_dwordx4).
__device__ __forceinline__ void async16(const void* g, void* l) {
  __builtin_amdgcn_global_load_lds((gu32*)g, (lu32*)l, 16, 0, 0);
}

// W-only compact pass: 1024x1024 fp32 masked weight -> 1024x512 bf16.
// Tiny (~9 MiB read, 1 MiB write, ~2 us). X compaction is fused into the GEMM.
__global__ __launch_bounds__(256) void wcompact_kernel(
    const float* __restrict__ w, const float* __restrict__ msk,
    unsigned short* __restrict__ wb) {
  const int i = blockIdx.x * 256 + threadIdx.x;  // 131072 windows of 8 cols
  const int wi = i & 127;
  const int row = i >> 7;  // 0..1023
  const float* p = w + (size_t)row * KDIM + wi * 8;
  f32x4 a = *(const f32x4*)p;
  f32x4 b = *(const f32x4*)(p + 4);
  f32x4 moa = *(const f32x4*)(msk + (size_t)row * KDIM + wi * 8);  // own-row mask
  f32x4 mob = *(const f32x4*)(msk + (size_t)row * KDIM + wi * 8 + 4);
  f32x4 ma = *(const f32x4*)(msk + wi * 8);                        // row-0 pattern
  f32x4 mb = *(const f32x4*)(msk + wi * 8 + 4);
#pragma unroll
  for (int t = 0; t < 4; ++t) { a[t] *= moa[t]; b[t] *= mob[t]; }  // faithful w*mask
  u16x4 o;
  o[0] = f2bf(sel_first(a, ma));
  o[1] = f2bf(sel_second(a, ma));
  o[2] = f2bf(sel_first(b, mb));
  o[3] = f2bf(sel_second(b, mb));
  ((u16x4*)wb)[i] = o;
}

// ---------------------------------------------------------------------------
// Fused GEMM: C[128x256 tile] = compact(X) * Wb^T over compacted K.
//  - 4 waves / 256 threads; wave = full 128 M-rows x 64 N-cols; acc[8][4] f32x4.
//  - A reg-staged (T14): 16 f32x4 X loads issued at loop TOP (latency hides
//    under MFMA), 2:4-select + bf16-convert AFTER compute (mask reloaded
//    L1-hot), swizzled ds_write after barrier. Single LDS buffer (regs are
//    the second buffer).
//  - B via global_load_lds from pre-compacted Wb, double-buffered; prefetch
//    issued mid-compute so the __syncthreads vmcnt-drain finds it landed.
//  - LDS 16 + 64 = 80 KiB -> 2 blocks/CU (inter-block MFMA/VALU overlap).
//  - Numerically identical to the two-pass version (same select + f2bf +
//    MFMA order) -> same absmax.
// ---------------------------------------------------------------------------
__global__ __launch_bounds__(256, 2) void gemm_fused_kernel(
    const float* __restrict__ X, const unsigned short* __restrict__ Bb,
    const float* __restrict__ msk, float* __restrict__ C) {
  __shared__ __align__(16) unsigned short lA[128 * 64];     // 16 KiB
  __shared__ __align__(16) unsigned short lB[2][256 * 64];  // 64 KiB

  const int tid = threadIdx.x;
  // XCD swizzle: 1024 blocks, %8==0 -> bijective. The 4 nt-sharers of an
  // A-panel are consecutive locals on one XCD -> X re-reads hit its L2.
  const int g = blockIdx.x;
  const int xcd = g & 7;
  const int local = g >> 3;                // 0..127
  const int nt = local & 3;                // N/256 = 4 tiles
  const int mt = xcd * 32 + (local >> 2);  // M/128 = 256 tiles
  const int m0 = mt * 128, n0 = nt * 256;
  const int lane = tid & 63, wv = tid >> 6;
  const int q = lane >> 4, r = lane & 15;
  const int wn = wv * 64;

  f32x4 acc[8][4] = {};

  // A staging coords: 4 chunks/thread; stored slot p&7 holds logical chunk
  // lc = (p&7)^(row&7) so swizzled fragment reads are conflict-free.
  int arow[4], alc[4];
#pragma unroll
  for (int i = 0; i < 4; ++i) {
    const int p = i * 256 + tid;
    arow[i] = p >> 3;
    alc[i] = (p & 7) ^ (arow[i] & 7);
  }
  // B staging coords: 8 chunks/thread (256 rows x 64 kc).
  int brow[8], bcg[8];
#pragma unroll
  for (int i = 0; i < 8; ++i) {
    const int p = i * 256 + tid;
    brow[i] = p >> 3;
    bcg[i] = (p & 7) ^ (brow[i] & 7);
  }

  auto loadX = [&](int kt, f32x4* xa) {
#pragma unroll
    for (int i = 0; i < 4; ++i) {
      const float* src = X + (size_t)(m0 + arow[i]) * KDIM + kt * 128 + alc[i] * 16;
      xa[4 * i + 0] = ((const f32x4*)src)[0];
      xa[4 * i + 1] = ((const f32x4*)src)[1];
      xa[4 * i + 2] = ((const f32x4*)src)[2];
      xa[4 * i + 3] = ((const f32x4*)src)[3];
    }
  };
  auto stageB = [&](int kt, int buf) {
#pragma unroll
    for (int i = 0; i < 8; ++i) {
      const int p = i * 256 + tid;
      async16(Bb + (size_t)(n0 + brow[i]) * KC + kt * 64 + bcg[i] * 8,
              &lB[buf][p * 8]);
    }
  };
  // mask row-0 reloaded here: 4 KiB, L1-hot after the first tile.
  auto convertA = [&](int kt, const f32x4* xa, u16x8* oc) {
#pragma unroll
    for (int i = 0; i < 4; ++i) {
      const float* mp = msk + kt * 128 + alc[i] * 16;
      f32x4 mv0 = ((const f32x4*)mp)[0];
      f32x4 mv1 = ((const f32x4*)mp)[1];
      f32x4 mv2 = ((const f32x4*)mp)[2];
      f32x4 mv3 = ((const f32x4*)mp)[3];
      u16x8 o;
      o[0] = f2bf(sel_first (xa[4 * i + 0], mv0));
      o[1] = f2bf(sel_second(xa[4 * i + 0], mv0));
      o[2] = f2bf(sel_first (xa[4 * i + 1], mv1));
      o[3] = f2bf(sel_second(xa[4 * i + 1], mv1));
      o[4] = f2bf(sel_first (xa[4 * i + 2], mv2));
      o[5] = f2bf(sel_second(xa[4 * i + 2], mv2));
      o[6] = f2bf(sel_first (xa[4 * i + 3], mv3));
      o[7] = f2bf(sel_second(xa[4 * i + 3], mv3));
      oc[i] = o;
    }
  };
  auto writeA = [&](const u16x8* oc) {
#pragma unroll
    for (int i = 0; i < 4; ++i)
      *(u16x8*)&lA[(i * 256 + tid) * 8] = oc[i];
  };

  // prologue: stage tile 0 (A regs + convert + write, B async into buf 0)
  {
    f32x4 xa[16];
    u16x8 oc[4];
    loadX(0, xa);
    stageB(0, 0);
    convertA(0, xa, oc);
    writeA(oc);
  }
  __syncthreads();  // drains vmcnt (B0 asyncs) + lgkm (A writes)

  for (int kt = 0; kt < 8; ++kt) {  // KC/64 = 8 K-tiles
    const int cur = kt & 1;
    f32x4 xa[16];
    if (kt < 7) loadX(kt + 1, xa);  // issue early; consumed after compute

    const unsigned short* sB = &lB[cur][0];
#pragma unroll
    for (int kk = 0; kk < 2; ++kk) {
      s16x8 bv[4];
#pragma unroll
      for (int j = 0; j < 4; ++j) {
        const int br = wn + 16 * j + r;
        bv[j] = *(const s16x8*)&sB[br * 64 + (((kk << 2) | q) ^ (br & 7)) * 8];
      }
#pragma unroll
      for (int mh = 0; mh < 2; ++mh) {
        s16x8 av[4];
#pragma unroll
        for (int i = 0; i < 4; ++i) {
          const int ar = 64 * mh + 16 * i + r;
          av[i] = *(const s16x8*)&lA[ar * 64 + (((kk << 2) | q) ^ (ar & 7)) * 8];
        }
#pragma unroll
        for (int i = 0; i < 4; ++i)
#pragma unroll
          for (int j = 0; j < 4; ++j)
            acc[4 * mh + i][j] = __builtin_amdgcn_mfma_f32_16x16x32_bf16(
                bv[j], av[i], acc[4 * mh + i][j], 0, 0, 0);
      }
      // B prefetch mid-compute: lands well before the next tile's barrier
      // drain; writes the other buffer (WAR-safe: its last readers finished
      // before this iteration's entry barrier).
      if (kk == 0 && kt < 7) stageB(kt + 1, cur ^ 1);
    }

    if (kt < 7) {
      u16x8 oc[4];
      convertA(kt + 1, xa, oc);  // X regs die here; mask loads are L1-hot
      __syncthreads();           // all waves done reading lA / lB[cur]
      writeA(oc);
      __syncthreads();           // A(kt+1) visible; vmcnt drain -> B landed
    }
  }

  // epilogue (transposed fragment, verified mapping):
  // acc[a][j][t] = C[m0 + 64*(a>>2) + 16*(a&3) + r][n0 + wn + 16j + 4q + t]
#pragma unroll
  for (int a = 0; a < 8; ++a) {
    const size_t row = (size_t)(m0 + 64 * (a >> 2) + 16 * (a & 3) + r);
    float* crow = C + row * NDIM + n0 + wn + 4 * q;
#pragma unroll
    for (int j = 0; j < 4; ++j)
      *(f32x4*)(crow + 16 * j) = acc[a][j];
  }
}

// ---------------------------------------------------------------------------
// Fallback (ws too small for even Wb): dense K=1024 GEMM, fp32 loads with
// in-reg convert + masked W. Unchanged from the verified 128^2 kernel.
// ---------------------------------------------------------------------------
__global__ __launch_bounds__(256) void gemm_dense_kernel(
    const float* __restrict__ Af, const float* __restrict__ Wf,
    const float* __restrict__ Mf, float* __restrict__ C) {
  __shared__ __align__(16) unsigned short lA[128 * 64];
  __shared__ __align__(16) unsigned short lB[128 * 64];

  constexpr int kstr = KDIM;
  constexpr int kiters = kstr / 64;

  const int tid = threadIdx.x;
  const int g = blockIdx.x;  // 2048 blocks
  const int xcd = g & 7;
  const int local = g >> 3;
  const int nt = local & 7;
  const int mt = xcd * 32 + (local >> 3);
  const int m0 = mt * 128, n0 = nt * 128;
  const int lane = tid & 63;
  const int wv = tid >> 6;
  const int q = lane >> 4, r = lane & 15;
  const int wm = (wv >> 1) * 64, wn = (wv & 1) * 64;

  f32x4 acc[4][4] = {};

  int prow[4], pcg[4];
#pragma unroll
  for (int i = 0; i < 4; ++i) {
    const int p = i * 256 + tid;
    prow[i] = p >> 3;
    pcg[i] = (p & 7) ^ (prow[i] & 7);
  }

  for (int kt = 0; kt < kiters; ++kt) {
    const int k0 = kt * 64;
#pragma unroll
    for (int i = 0; i < 4; ++i) {
      const int p = i * 256 + tid;
      const size_t offA = (size_t)(m0 + prow[i]) * kstr + k0 + pcg[i] * 8;
      const size_t offB = (size_t)(n0 + prow[i]) * kstr + k0 + pcg[i] * 8;
      f32x4 a0 = *(const f32x4*)(Af + offA);
      f32x4 a1 = *(const f32x4*)(Af + offA + 4);
      f32x4 w0 = *(const f32x4*)(Wf + offB);
      f32x4 w1 = *(const f32x4*)(Wf + offB + 4);
      f32x4 k0v = *(const f32x4*)(Mf + offB);
      f32x4 k1v = *(const f32x4*)(Mf + offB + 4);
      u16x8 oa, ob;
#pragma unroll
      for (int t = 0; t < 4; ++t) {
        oa[t] = f2bf(a0[t]); oa[4 + t] = f2bf(a1[t]);
        ob[t] = f2bf(w0[t] * k0v[t]); ob[4 + t] = f2bf(w1[t] * k1v[t]);
      }
      *(u16x8*)&lA[p * 8] = oa;
      *(u16x8*)&lB[p * 8] = ob;
    }
    __syncthreads();
#pragma unroll
    for (int kk = 0; kk < 2; ++kk) {
      s16x8 av[4], bv[4];
#pragma unroll
      for (int i = 0; i < 4; ++i) {
        const int ar = wm + 16 * i + r;
        av[i] = *(const s16x8*)&lA[ar * 64 + (((kk << 2) | q) ^ (ar & 7)) * 8];
        const int br = wn + 16 * i + r;
        bv[i] = *(const s16x8*)&lB[br * 64 + (((kk << 2) | q) ^ (br & 7)) * 8];
      }
#pragma unroll
      for (int i = 0; i < 4; ++i)
#pragma unroll
        for (int j = 0; j < 4; ++j)
          acc[i][j] = __builtin_amdgcn_mfma_f32_16x16x32_bf16(bv[j], av[i],
                                                              acc[i][j], 0, 0, 0);
    }
    __syncthreads();
  }

#pragma unroll
  for (int i = 0; i < 4; ++i) {
    const size_t rowoff = (size_t)(m0 + wm + 16 * i + r) * NDIM;
#pragma unroll
    for (int j = 0; j < 4; ++j) {
      const int col = n0 + wn + 16 * j + 4 * q;
      *(f32x4*)&C[rowoff + col] = acc[i][j];
    }
  }
}

extern "C" void kernel_launch(void* const* d_in, const int* in_sizes, int n_in,
                              void* d_out, int out_size, void* d_ws, size_t ws_size,
                              hipStream_t stream) {
  (void)in_sizes; (void)n_in; (void)out_size;
  const float* x  = (const float*)d_in[0];
  const float* w  = (const float*)d_in[1];
  const float* mk = (const float*)d_in[2];
  float* out = (float*)d_out;

  const size_t wb_bytes = (size_t)NDIM * KC * 2;  // 1 MiB

  if (ws_size >= wb_bytes) {
    unsigned short* wb = (unsigned short*)d_ws;
    hipLaunchKernelGGL(wcompact_kernel, dim3(NDIM * KDIM / 8 / 256), dim3(256), 0,
                       stream, w, mk, wb);
    const int gemm_blocks = (MDIM / 128) * (NDIM / 256);  // 1024
    hipLaunchKernelGGL(gemm_fused_kernel, dim3(gemm_blocks), dim3(256), 0, stream,
                       x, wb, mk, out);
  } else {
    const int gemm_blocks = (MDIM / 128) * (NDIM / 128);  // 2048
    hipLaunchKernelGGL(gemm_dense_kernel, dim3(gemm_blocks), dim3(256), 0, stream,
                       x, w, mk, out);
  }
}